// Round 7
// baseline (387.314 us; speedup 1.0000x reference)
//
#include <hip/hip_runtime.h>
#include <hip/hip_cooperative_groups.h>
namespace cg = cooperative_groups;

// Sizes fixed by the problem.
#define Bz 4
#define Nn 8192
#define Dd 512
#define Ll 64
#define Pp 128
#define Ww 64
#define Ss 32
#define NW 4   // number of window starts per segment

// ---------------------------------------------------------------------------
// ONE cooperative kernel, 256 blocks x 1024 threads (1 block/CU, co-resident).
// Phase A (pre):  blocks 0..191 GEMM tiles (M1/M2/WvoT, 64x64, 4x4 blocking,
//                 256 active threads); 192..199 vb8; 200..203 coord stats.
// Phase B (qkg):  all 256 blocks: QK/G 128-col chunks + sqk4/qb2 scalars.
// Phase C (attn): all 256 blocks: R6 attn2 body verbatim (1024 threads).
// grid.sync() + threadfence between phases. LDS: one 48 KB arena, aliased
// per phase (phases are time-disjoint). All __syncthreads hoisted to
// block-uniform control flow (guarded bodies, unguarded barriers).
__global__ __launch_bounds__(1024) void fused(
    const float* __restrict__ feats, const float* __restrict__ coords,
    const float* __restrict__ z,  const float* __restrict__ Wq,
    const float* __restrict__ Wk, const float* __restrict__ W2,
    const float* __restrict__ b2, const float* __restrict__ Wv,
    const float* __restrict__ Wo, const float* __restrict__ W1,
    const float* __restrict__ b1, const float* __restrict__ bo,
    float* cstats, float* M1, float* M2, float* WvoT, float* vb8,
    float* QK, float* G, float* sqk4, float* qb2, float* out) {
    cg::grid_group grid = cg::this_grid();
    __shared__ __align__(16) char smem[48256];
    int bid = blockIdx.x, tid = threadIdx.x;

    // ================= phase A: preprocessing =================
    {
        bool act = (tid < 256);
        int wv4 = tid >> 6, lane = tid & 63;        // valid for tid<256
        if (bid < 192) {
            float (*As)[68] = (float (*)[68])smem;              // [k][m]
            float (*Bs)[68] = (float (*)[68])(smem + 17408);    // [k][n]
            int role = bid >> 6;            // 0=M1, 1=M2, 2=WvoT
            int wb = bid & 63;
            int m0 = (wb >> 3) * 64;
            int n0 = (wb & 7) * 64;
            const float* Amat = (role == 2) ? Wv : Wq;
            const float* Bmat = (role == 0) ? Wk : (role == 1) ? W2 : Wo;
            float* Cmat = (role == 0) ? M1 : (role == 1) ? M2 : WvoT;
            int tx = tid & 15, ty = (tid & 255) >> 4;   // 16x16 grid, 4x4 each
            float4 acc[4];
#pragma unroll
            for (int i = 0; i < 4; ++i) acc[i] = make_float4(0.f, 0.f, 0.f, 0.f);

            for (int k0 = 0; k0 < Dd; k0 += 64) {
                if (act) {
                    int kk = tid >> 4, q4 = (tid & 15) * 4;
#pragma unroll
                    for (int i = 0; i < 4; ++i) {
                        int k = kk + 16 * i;
                        *(float4*)&As[k][q4] =
                            *(const float4*)&Amat[(size_t)(k0 + k) * Dd + m0 + q4];
                    }
                    if (role != 2) {
#pragma unroll
                        for (int i = 0; i < 4; ++i) {
                            int k = kk + 16 * i;
                            *(float4*)&Bs[k][q4] =
                                *(const float4*)&Bmat[(size_t)(k0 + k) * Dd + n0 + q4];
                        }
                    } else {
                        // B = Wo[d][c]: coalesced rows, transpose-store Bs[c][d]
                        int d = tid >> 2;
#pragma unroll
                        for (int j = 0; j < 4; ++j) {
                            int c0 = (tid & 3) * 16 + 4 * j;
                            float4 v = *(const float4*)&Bmat[(size_t)(n0 + d) * Dd + k0 + c0];
                            Bs[c0 + 0][d] = v.x; Bs[c0 + 1][d] = v.y;
                            Bs[c0 + 2][d] = v.z; Bs[c0 + 3][d] = v.w;
                        }
                    }
                }
                __syncthreads();
                if (act) {
#pragma unroll 8
                    for (int kk = 0; kk < 64; ++kk) {
                        float4 a4 = *(const float4*)&As[kk][ty * 4];
                        float4 b4 = *(const float4*)&Bs[kk][tx * 4];
                        acc[0].x = fmaf(a4.x, b4.x, acc[0].x); acc[0].y = fmaf(a4.x, b4.y, acc[0].y);
                        acc[0].z = fmaf(a4.x, b4.z, acc[0].z); acc[0].w = fmaf(a4.x, b4.w, acc[0].w);
                        acc[1].x = fmaf(a4.y, b4.x, acc[1].x); acc[1].y = fmaf(a4.y, b4.y, acc[1].y);
                        acc[1].z = fmaf(a4.y, b4.z, acc[1].z); acc[1].w = fmaf(a4.y, b4.w, acc[1].w);
                        acc[2].x = fmaf(a4.z, b4.x, acc[2].x); acc[2].y = fmaf(a4.z, b4.y, acc[2].y);
                        acc[2].z = fmaf(a4.z, b4.z, acc[2].z); acc[2].w = fmaf(a4.z, b4.w, acc[2].w);
                        acc[3].x = fmaf(a4.w, b4.x, acc[3].x); acc[3].y = fmaf(a4.w, b4.y, acc[3].y);
                        acc[3].z = fmaf(a4.w, b4.z, acc[3].z); acc[3].w = fmaf(a4.w, b4.w, acc[3].w);
                    }
                }
                __syncthreads();
            }
            if (act) {
#pragma unroll
                for (int i = 0; i < 4; ++i)
                    *(float4*)&Cmat[(size_t)(m0 + ty * 4 + i) * Dd + n0 + tx * 4] = acc[i];
            }
        } else if (bid < 200) {
            float* b2s = (float*)(smem + 34816);
            int j = bid - 192;
            if (act && tid < 64) b2s[tid] = b2[j * 64 + tid];
            __syncthreads();
            if (act) {
                float a0 = 0.f, a1 = 0.f;
#pragma unroll 4
                for (int ee = 0; ee < 64; ++ee) {
                    int e = j * 64 + ee;
                    float be = b2s[ee];
                    a0 = fmaf(be, Wq[(size_t)e * Dd + tid], a0);
                    a1 = fmaf(be, Wq[(size_t)e * Dd + tid + 256], a1);
                }
                vb8[j * Dd + tid] = a0;
                vb8[j * Dd + tid + 256] = a1;
            }
        } else if (bid < 204) {
            double* dred = (double*)(smem + 35072);
            int b = bid - 200;
            if (act) {
                double sx = 0, sy = 0, sxx = 0, syy = 0;
                const float4* cp = (const float4*)(coords + (size_t)b * Nn * 2);
                for (int i = tid; i < Nn / 2; i += 256) {
                    float4 v = cp[i];
                    sx  += (double)v.x + (double)v.z;
                    sy  += (double)v.y + (double)v.w;
                    sxx += (double)v.x * v.x + (double)v.z * v.z;
                    syy += (double)v.y * v.y + (double)v.w * v.w;
                }
                for (int o = 32; o > 0; o >>= 1) {
                    sx  += __shfl_down(sx,  o); sy  += __shfl_down(sy,  o);
                    sxx += __shfl_down(sxx, o); syy += __shfl_down(syy, o);
                }
                if (lane == 0) {
                    dred[wv4 * 4 + 0] = sx;  dred[wv4 * 4 + 1] = sy;
                    dred[wv4 * 4 + 2] = sxx; dred[wv4 * 4 + 3] = syy;
                }
            }
            __syncthreads();
            if (tid == 0) {
                double tx = 0, ty = 0, txx = 0, tyy = 0;
                for (int i = 0; i < 4; ++i) {
                    tx += dred[i * 4 + 0]; ty += dred[i * 4 + 1];
                    txx += dred[i * 4 + 2]; tyy += dred[i * 4 + 3];
                }
                const double N = (double)Nn;
                double mux = tx / N, muy = ty / N;
                double vx = (txx - N * mux * mux) / (N - 1.0);
                double vy = (tyy - N * muy * muy) / (N - 1.0);
                cstats[b * 4 + 0] = (float)mux;
                cstats[b * 4 + 1] = (float)muy;
                cstats[b * 4 + 2] = (float)sqrt(vx) + 1e-8f;
                cstats[b * 4 + 3] = (float)sqrt(vy) + 1e-8f;
            }
        }
        // blocks >= 204: nothing
    }
    __threadfence();
    grid.sync();

    // ================= phase B: QK/G from M1/M2 =================
    {
        float* zs        = (float*)smem;                    // [512]
        float (*pq)[128] = (float (*)[128])(smem + 2048);   // [8][128]
        float (*pg)[128] = (float (*)[128])(smem + 6144);
        float* redB      = (float*)(smem + 10240);          // [8]
        bool act = (tid < 256);
        int l = bid & 63, ch = bid >> 6;
        int wv4 = tid >> 6, lane = tid & 63;

        if (act) {
            zs[tid]       = z[(size_t)l * Dd + tid];
            zs[tid + 256] = z[(size_t)l * Dd + tid + 256];
        }
        __syncthreads();
        if (act) {
            if (ch == 0) {
                float vba = 0.f, vbb = 0.f;
#pragma unroll
                for (int j = 0; j < 8; ++j) {
                    vba += vb8[j * Dd + tid];
                    vbb += vb8[j * Dd + tid + 256];
                }
                float p = zs[tid] * vba + zs[tid + 256] * vbb;
                for (int o = 32; o > 0; o >>= 1) p += __shfl_xor(p, o);
                if (lane == 0) redB[4 + wv4] = p;
            }
            int qd = tid & 31, h = tid >> 5;
            int cb = ch * 128 + qd * 4;
            float4 aq = make_float4(0.f, 0.f, 0.f, 0.f);
            float4 ag = make_float4(0.f, 0.f, 0.f, 0.f);
            for (int d = h * 64; d < h * 64 + 64; ++d) {
                float zd = zs[d];
                float4 m1 = *(const float4*)&M1[(size_t)d * Dd + cb];
                float4 m2 = *(const float4*)&M2[(size_t)d * Dd + cb];
                aq.x = fmaf(zd, m1.x, aq.x); aq.y = fmaf(zd, m1.y, aq.y);
                aq.z = fmaf(zd, m1.z, aq.z); aq.w = fmaf(zd, m1.w, aq.w);
                ag.x = fmaf(zd, m2.x, ag.x); ag.y = fmaf(zd, m2.y, ag.y);
                ag.z = fmaf(zd, m2.z, ag.z); ag.w = fmaf(zd, m2.w, ag.w);
            }
            *(float4*)&pq[h][qd * 4] = aq;
            *(float4*)&pg[h][qd * 4] = ag;
        }
        __syncthreads();
        if (act && tid < 128) {
            float vq = 0.f, vg = 0.f;
#pragma unroll
            for (int hh = 0; hh < 8; ++hh) { vq += pq[hh][tid]; vg += pg[hh][tid]; }
            QK[(size_t)l * Dd + ch * 128 + tid] = vq;
            G [(size_t)l * Dd + ch * 128 + tid] = vg;
            float s = vq;
            for (int o = 32; o > 0; o >>= 1) s += __shfl_xor(s, o);
            if (lane == 0) redB[wv4] = s;       // wv4 in {0,1}
        }
        __syncthreads();
        if (tid == 0) sqk4[ch * 64 + l] = redB[0] + redB[1];
        if (ch == 0 && tid == 32) qb2[l] = redB[4] + redB[5] + redB[6] + redB[7];
    }
    __threadfence();
    grid.sync();

    // ================= phase C: attention + output projection =================
    {
        float*  qk_s  = (float*)smem;                       // [512]; reused as fm
        float4* wpack = (float4*)(smem + 2048);             // [512] {w1a,w1b,b1,g}
        float*  scx   = (float*)(smem + 10240);             // [128]
        float*  scy   = (float*)(smem + 10752);
        float*  smu   = (float*)(smem + 11264);
        float*  srs   = (float*)(smem + 11776);
        float*  sa    = (float*)(smem + 12288);
        float*  shs   = (float*)(smem + 12800);             // [256]
        float (*sar)[Ww] = (float (*)[Ww])(smem + 13824);   // [4][64]
        float*  swt   = (float*)(smem + 14848);             // [128]
        float*  s2red = (float*)(smem + 15360);             // [4]
        float*  soff  = (float*)(smem + 15376);             // [1]
        float (*red16)[Dd] = (float (*)[Dd])(smem + 15392); // [16][512]

        int bx = bid;                       // b*64 + l
        int l = bx & 63, b = bx >> 6;
        int wv = tid >> 6, lane = tid & 63; // 16 waves

        // ---- stage (global -> LDS) ----
        if (tid < Dd) {
            qk_s[tid] = QK[l * Dd + tid];
        } else {
            int t = tid - Dd;
            wpack[t] = make_float4(W1[2 * t], W1[2 * t + 1], b1[t], G[l * Dd + t]);
        }
        if (tid < Pp) {
            int row = bx * Pp + tid;
            float x = coords[(size_t)row * 2], y = coords[(size_t)row * 2 + 1];
            scx[tid] = (x - cstats[b * 4 + 0]) / cstats[b * 4 + 2];
            scy[tid] = (y - cstats[b * 4 + 1]) / cstats[b * 4 + 3];
        }
        float sqk_l = sqk4[l] + sqk4[64 + l] + sqk4[128 + l] + sqk4[192 + l];
        float qb2_l = qb2[l];
        __syncthreads();

        // ---- issue ALL feats loads (8 rows/wave) ----
        const float* fbase = feats + (size_t)bx * Pp * Dd;
        int rb = wv * 8;
        float4 f0[8], f1[8];
#pragma unroll
        for (int i = 0; i < 8; ++i) {
            const float4* fr = (const float4*)(fbase + (size_t)(rb + i) * Dd);
            f0[i] = fr[lane];
            f1[i] = fr[lane + 64];
        }
        __builtin_amdgcn_sched_barrier(0);  // pin: loads stay above pos-bias

        // ---- window coord means, per-wave in registers ----
        float cmx[4], cmy[4];
#pragma unroll
        for (int n = 0; n < 4; ++n) {
            int nv = (n == 3) ? 32 : 64;
            float cx = (lane < nv) ? scx[n * Ss + lane] : 0.f;
            float cy = (lane < nv) ? scy[n * Ss + lane] : 0.f;
            for (int o = 32; o > 0; o >>= 1) { cx += __shfl_xor(cx, o); cy += __shfl_xor(cy, o); }
            cmx[n] = cx / (float)nv; cmy[n] = cy / (float)nv;
        }

        // ---- pos-bias (LDS phase; HBM loads stream underneath) ----
        {
            int s = tid >> 2, q = tid & 3;
            int n = s >> 6, w = s & 63;
            int nv = (n == 3) ? 32 : 64;
            float hs = 0.f;
            if (w < nv) {
                int p = n * Ss + w;
                float px = scx[p] - cmx[n], py = scy[p] - cmy[n];
                int d0 = q * 128;
#pragma unroll 4
                for (int d = d0; d < d0 + 128; ++d) {
                    float4 c = wpack[d];
                    hs = fmaf(c.w, fmaxf(fmaf(c.x, px, fmaf(c.y, py, c.z)), 0.f), hs);
                }
            }
            hs += __shfl_xor(hs, 1);
            hs += __shfl_xor(hs, 2);
            if (q == 0) shs[s] = hs;
        }

        // ---- row stats from registers (consumes the loads) ----
        {
            float4 q0 = ((const float4*)qk_s)[lane];
            float4 q1 = ((const float4*)qk_s)[lane + 64];
#pragma unroll
            for (int b2i = 0; b2i < 8; b2i += 4) {
                float sP[4], ssP[4], aP[4];
#pragma unroll
                for (int i = 0; i < 4; ++i) {
                    float4 v0 = f0[b2i + i], v1 = f1[b2i + i];
                    sP[i]  = v0.x + v0.y + v0.z + v0.w + v1.x + v1.y + v1.z + v1.w;
                    ssP[i] = v0.x * v0.x + v0.y * v0.y + v0.z * v0.z + v0.w * v0.w
                           + v1.x * v1.x + v1.y * v1.y + v1.z * v1.z + v1.w * v1.w;
                    aP[i]  = v0.x * q0.x + v0.y * q0.y + v0.z * q0.z + v0.w * q0.w
                           + v1.x * q1.x + v1.y * q1.y + v1.z * q1.z + v1.w * q1.w;
                }
#pragma unroll
                for (int o = 32; o > 0; o >>= 1) {
#pragma unroll
                    for (int i = 0; i < 4; ++i) {
                        sP[i] += __shfl_xor(sP[i], o); ssP[i] += __shfl_xor(ssP[i], o);
                        aP[i] += __shfl_xor(aP[i], o);
                    }
                }
                if (lane == 0) {
#pragma unroll
                    for (int i = 0; i < 4; ++i) {
                        int r = rb + b2i + i;
                        float mu  = sP[i] * (1.f / (float)Dd);
                        float var = ssP[i] * (1.f / (float)Dd) - mu * mu;
                        smu[r] = mu; srs[r] = 1.f / sqrtf(var + 1e-5f); sa[r] = aP[i];
                    }
                }
            }
        }
        __syncthreads();

        // ---- softmax per window (waves 0..3) ----
        const float invtemp = 0.04419417382415922f; // 1/sqrt(512)
        if (wv < 4) {
            int n = wv, w = lane;
            int nv = (n == 3) ? 32 : 64;
            int p = n * Ss + ((w < nv) ? w : 0);
            float lg = -1e30f;
            if (w < nv) {
                lg = (srs[p] * (sa[p] - smu[p] * sqk_l) + shs[n * Ww + w] + qb2_l) * invtemp;
                lg = fminf(fmaxf(lg, -10.f), 10.f);
            }
            float m = lg;
            for (int o = 32; o > 0; o >>= 1) m = fmaxf(m, __shfl_xor(m, o));
            float e = (w < nv) ? expf(lg - m) : 0.f;
            float ssum = e;
            for (int o = 32; o > 0; o >>= 1) ssum += __shfl_xor(ssum, o);
            float ar = (w < nv) ? (e / ssum) * srs[p] : 0.f;
            sar[n][w] = ar;
            float t2 = (w < nv) ? ar * smu[p] : 0.f;
            for (int o = 32; o > 0; o >>= 1) t2 += __shfl_xor(t2, o);
            if (lane == 0) s2red[n] = t2;
        }
        __syncthreads();

        // ---- combine per-row weights across (<=2) covering windows ----
        if (tid < Pp) {
            int p = tid;
            int na = (p >> 5) - 1, nb = (p >> 5);
            float wt = 0.f;
            if (na >= 0 && na <= 3) wt += sar[na][p - na * Ss];
            if (nb <= 3)            wt += sar[nb][p - nb * Ss];
            swt[p] = wt;
        }
        if (tid == 0) *soff = 0.25f * (s2red[0] + s2red[1] + s2red[2] + s2red[3]);
        __syncthreads();

        // ---- pass 2: weighted feature sum FROM REGISTERS ----
        {
            float4 a0 = make_float4(0.f, 0.f, 0.f, 0.f);
            float4 a1 = make_float4(0.f, 0.f, 0.f, 0.f);
#pragma unroll
            for (int i = 0; i < 8; ++i) {
                float wt = swt[rb + i];     // wave-uniform LDS broadcast
                a0.x = fmaf(wt, f0[i].x, a0.x); a0.y = fmaf(wt, f0[i].y, a0.y);
                a0.z = fmaf(wt, f0[i].z, a0.z); a0.w = fmaf(wt, f0[i].w, a0.w);
                a1.x = fmaf(wt, f1[i].x, a1.x); a1.y = fmaf(wt, f1[i].y, a1.y);
                a1.z = fmaf(wt, f1[i].z, a1.z); a1.w = fmaf(wt, f1[i].w, a1.w);
            }
            *(float4*)&red16[wv][lane * 4]       = a0;
            *(float4*)&red16[wv][256 + lane * 4] = a1;
        }
        __syncthreads();
        if (tid < Dd) {
            float v = 0.f;
#pragma unroll
            for (int w = 0; w < 16; ++w) v += red16[w][tid];
            qk_s[tid] = 0.25f * v - *soff;  // qk_s reused as fm
        }
        __syncthreads();

        // ---- tail: out = fm @ WvoT + bo (coalesced, L2-resident WvoT) ----
        {
            int h = tid >> 7, cq = (tid & 127) * 4;     // 8 e-groups of 64
            float4 acc = make_float4(0.f, 0.f, 0.f, 0.f);
#pragma unroll 4
            for (int e = h * 64; e < h * 64 + 64; ++e) {
                float fe = qk_s[e];
                float4 w = *(const float4*)&WvoT[(size_t)e * Dd + cq];
                acc.x = fmaf(fe, w.x, acc.x);
                acc.y = fmaf(fe, w.y, acc.y);
                acc.z = fmaf(fe, w.z, acc.z);
                acc.w = fmaf(fe, w.w, acc.w);
            }
            *(float4*)&red16[h][cq] = acc;
        }
        __syncthreads();
        if (tid < Dd) {
            out[(size_t)bx * Dd + tid] = bo[tid]
                + red16[0][tid] + red16[1][tid] + red16[2][tid] + red16[3][tid]
                + red16[4][tid] + red16[5][tid] + red16[6][tid] + red16[7][tid];
        }
    }
}

// ---------------------------------------------------------------------------
extern "C" void kernel_launch(void* const* d_in, const int* in_sizes, int n_in,
                              void* d_out, int out_size, void* d_ws, size_t ws_size,
                              hipStream_t stream) {
    const float* feats  = (const float*)d_in[0];
    const float* coords = (const float*)d_in[1];
    // d_in[2] = mask, unused (all false, and unused by the reference body)
    const float* z  = (const float*)d_in[3];
    const float* Wq = (const float*)d_in[4];
    const float* Wk = (const float*)d_in[5];
    const float* Wv = (const float*)d_in[6];
    const float* W1 = (const float*)d_in[7];
    const float* b1 = (const float*)d_in[8];
    const float* W2 = (const float*)d_in[9];
    const float* b2 = (const float*)d_in[10];
    const float* Wo = (const float*)d_in[11];
    const float* bo = (const float*)d_in[12];
    float* out = (float*)d_out;

    // workspace layout (floats) — nothing needs pre-zeroing (~3.3 MB)
    float* ws = (float*)d_ws;
    float* cstats = ws;                         // 16
    float* M1     = ws + 16;                    // 512*512
    float* M2     = M1 + Dd * Dd;               // 512*512
    float* WvoT   = M2 + Dd * Dd;               // 512*512
    float* vb8    = WvoT + Dd * Dd;             // 8*512
    float* QK     = vb8 + 8 * Dd;               // 64*512
    float* G      = QK + Ll * Dd;               // 64*512
    float* sqk4   = G + Ll * Dd;                // 256
    float* qb2    = sqk4 + 256;                 // 64

    void* args[] = {
        (void*)&feats, (void*)&coords, (void*)&z, (void*)&Wq, (void*)&Wk,
        (void*)&W2, (void*)&b2, (void*)&Wv, (void*)&Wo, (void*)&W1,
        (void*)&b1, (void*)&bo,
        (void*)&cstats, (void*)&M1, (void*)&M2, (void*)&WvoT, (void*)&vb8,
        (void*)&QK, (void*)&G, (void*)&sqk4, (void*)&qb2, (void*)&out
    };
    hipLaunchCooperativeKernel((const void*)fused, dim3(256), dim3(1024),
                               args, 0, stream);
}

// Round 8
// 211.159 us; speedup vs baseline: 1.8342x; 1.8342x over previous
//
#include <hip/hip_runtime.h>

// Sizes fixed by the problem.
#define Bz 4
#define Nn 8192
#define Dd 512
#define Ll 64
#define Pp 128
#define Ww 64
#define Ss 32
#define NW 4   // number of window starts per segment

// ---------------------------------------------------------------------------
// pre1: fully parallel preprocessing, 204 blocks x 256 threads (R6 verbatim).
//   [0,64):    M1 = Wq^T @ Wk   (64x64 tiles, 4x4 register blocking)
//   [64,128):  M2 = Wq^T @ W2
//   [128,192): WvoT[e,d] = sum_c Wv[c,e] Wo[d,c]
//   [192,200): vb8[j] = partial Wq^T @ b2 over e in [j*64,(j+1)*64)
//   [200,204): per-batch coord stats (mean + std ddof=1)
__global__ __launch_bounds__(256) void pre1(
    const float* __restrict__ coords, const float* __restrict__ b2,
    const float* __restrict__ Wq, const float* __restrict__ Wk,
    const float* __restrict__ W2,
    const float* __restrict__ Wv, const float* __restrict__ Wo,
    float* __restrict__ cstats,
    float* __restrict__ M1, float* __restrict__ M2,
    float* __restrict__ WvoT, float* __restrict__ vb8) {
    __shared__ float As[64][68];    // [k][m], 272B rows (16B-aligned)
    __shared__ float Bs[64][68];    // [k][n]
    __shared__ float b2s[64];
    __shared__ double dred[16];
    int bid = blockIdx.x, tid = threadIdx.x;
    int wv = tid >> 6, lane = tid & 63;

    if (bid < 192) {
        int role = bid >> 6;            // 0=M1, 1=M2, 2=WvoT
        int wb = bid & 63;
        int m0 = (wb >> 3) * 64;
        int n0 = (wb & 7) * 64;
        const float* Amat = (role == 2) ? Wv : Wq;
        const float* Bmat = (role == 0) ? Wk : (role == 1) ? W2 : Wo;
        float* Cmat = (role == 0) ? M1 : (role == 1) ? M2 : WvoT;
        int tx = tid & 15, ty = tid >> 4;       // 16x16 thread grid, 4x4 each
        float4 acc[4];
#pragma unroll
        for (int i = 0; i < 4; ++i) acc[i] = make_float4(0.f, 0.f, 0.f, 0.f);

        for (int k0 = 0; k0 < Dd; k0 += 64) {
            {
                int kk = tid >> 4, q4 = (tid & 15) * 4;
#pragma unroll
                for (int i = 0; i < 4; ++i) {
                    int k = kk + 16 * i;
                    *(float4*)&As[k][q4] =
                        *(const float4*)&Amat[(size_t)(k0 + k) * Dd + m0 + q4];
                }
                if (role != 2) {
#pragma unroll
                    for (int i = 0; i < 4; ++i) {
                        int k = kk + 16 * i;
                        *(float4*)&Bs[k][q4] =
                            *(const float4*)&Bmat[(size_t)(k0 + k) * Dd + n0 + q4];
                    }
                } else {
                    // B = Wo[d][c]: read rows coalesced, transpose-store Bs[c][d]
                    int d = tid >> 2;
#pragma unroll
                    for (int j = 0; j < 4; ++j) {
                        int c0 = (tid & 3) * 16 + 4 * j;
                        float4 v = *(const float4*)&Bmat[(size_t)(n0 + d) * Dd + k0 + c0];
                        Bs[c0 + 0][d] = v.x; Bs[c0 + 1][d] = v.y;
                        Bs[c0 + 2][d] = v.z; Bs[c0 + 3][d] = v.w;
                    }
                }
            }
            __syncthreads();
#pragma unroll 8
            for (int kk = 0; kk < 64; ++kk) {
                float4 a4 = *(const float4*)&As[kk][ty * 4];
                float4 b4 = *(const float4*)&Bs[kk][tx * 4];
                acc[0].x = fmaf(a4.x, b4.x, acc[0].x); acc[0].y = fmaf(a4.x, b4.y, acc[0].y);
                acc[0].z = fmaf(a4.x, b4.z, acc[0].z); acc[0].w = fmaf(a4.x, b4.w, acc[0].w);
                acc[1].x = fmaf(a4.y, b4.x, acc[1].x); acc[1].y = fmaf(a4.y, b4.y, acc[1].y);
                acc[1].z = fmaf(a4.y, b4.z, acc[1].z); acc[1].w = fmaf(a4.y, b4.w, acc[1].w);
                acc[2].x = fmaf(a4.z, b4.x, acc[2].x); acc[2].y = fmaf(a4.z, b4.y, acc[2].y);
                acc[2].z = fmaf(a4.z, b4.z, acc[2].z); acc[2].w = fmaf(a4.z, b4.w, acc[2].w);
                acc[3].x = fmaf(a4.w, b4.x, acc[3].x); acc[3].y = fmaf(a4.w, b4.y, acc[3].y);
                acc[3].z = fmaf(a4.w, b4.z, acc[3].z); acc[3].w = fmaf(a4.w, b4.w, acc[3].w);
            }
            __syncthreads();
        }
#pragma unroll
        for (int i = 0; i < 4; ++i)
            *(float4*)&Cmat[(size_t)(m0 + ty * 4 + i) * Dd + n0 + tx * 4] = acc[i];
    } else if (bid < 200) {
        // ---- vb8 partial: e-range [j*64, j*64+64) ----
        int j = bid - 192;
        if (tid < 64) b2s[tid] = b2[j * 64 + tid];
        __syncthreads();
        float a0 = 0.f, a1 = 0.f;
#pragma unroll 4
        for (int ee = 0; ee < 64; ++ee) {
            int e = j * 64 + ee;
            float be = b2s[ee];
            a0 = fmaf(be, Wq[(size_t)e * Dd + tid], a0);
            a1 = fmaf(be, Wq[(size_t)e * Dd + tid + 256], a1);
        }
        vb8[j * Dd + tid] = a0;
        vb8[j * Dd + tid + 256] = a1;
    } else {
        // ---- coord stats ----
        int b = bid - 200;
        double sx = 0, sy = 0, sxx = 0, syy = 0;
        const float4* cp = (const float4*)(coords + (size_t)b * Nn * 2);
        for (int i = tid; i < Nn / 2; i += 256) {      // 2 points per float4
            float4 v = cp[i];
            sx  += (double)v.x + (double)v.z;
            sy  += (double)v.y + (double)v.w;
            sxx += (double)v.x * v.x + (double)v.z * v.z;
            syy += (double)v.y * v.y + (double)v.w * v.w;
        }
        for (int o = 32; o > 0; o >>= 1) {
            sx  += __shfl_down(sx,  o); sy  += __shfl_down(sy,  o);
            sxx += __shfl_down(sxx, o); syy += __shfl_down(syy, o);
        }
        if (lane == 0) {
            dred[wv * 4 + 0] = sx;  dred[wv * 4 + 1] = sy;
            dred[wv * 4 + 2] = sxx; dred[wv * 4 + 3] = syy;
        }
        __syncthreads();
        if (tid == 0) {
            double tx = 0, ty = 0, txx = 0, tyy = 0;
            for (int i = 0; i < 4; ++i) {
                tx += dred[i * 4 + 0]; ty += dred[i * 4 + 1];
                txx += dred[i * 4 + 2]; tyy += dred[i * 4 + 3];
            }
            const double N = (double)Nn;
            double mux = tx / N, muy = ty / N;
            double vx = (txx - N * mux * mux) / (N - 1.0);
            double vy = (tyy - N * muy * muy) / (N - 1.0);
            cstats[b * 4 + 0] = (float)mux;
            cstats[b * 4 + 1] = (float)muy;
            cstats[b * 4 + 2] = (float)sqrt(vx) + 1e-8f;
            cstats[b * 4 + 3] = (float)sqrt(vy) + 1e-8f;
        }
    }
}

// ---------------------------------------------------------------------------
// attn3 = R6 attn2 + in-block QK/G row computation (absorbs the qkg kernel).
// One block per (b,l), 1024 threads. Prologue: stage z/W1/b1/vb/coords ->
// issue feats loads -> compute QK[l,:]=z@M1, G[l,:]=z@M2 from L2-resident
// M1/M2 (overlaps feats HBM latency) -> reduce + sqk/qb2 in-block ->
// pos-bias -> row stats from registers -> softmax -> pass2 from registers ->
// tail out = fm @ WvoT + bo.
__global__ __launch_bounds__(1024) void attn3(
    const float* __restrict__ feats, const float* __restrict__ coords,
    const float* __restrict__ cstats,
    const float* __restrict__ M1, const float* __restrict__ M2,
    const float* __restrict__ vb8, const float* __restrict__ z,
    const float* __restrict__ W1, const float* __restrict__ b1,
    const float* __restrict__ WvoT, const float* __restrict__ bo,
    float* __restrict__ out) {
    __shared__ float  qk_s[Dd];             // QK row (computed); reused as fm
    __shared__ float  gw[Dd];               // G row (computed)
    __shared__ float  zs[Dd];               // z[l]
    __shared__ float4 wpack[Dd];            // {w1a, w1b, b1, vb}
    __shared__ float  scx[Pp], scy[Pp];
    __shared__ float  smu[Pp], srs[Pp], sa[Pp];
    __shared__ float  shs[NW * Ww];
    __shared__ float  sar[NW][Ww];
    __shared__ float  swt[Pp];
    __shared__ float  s2red[NW];
    __shared__ float  soff;
    __shared__ float  redsc[16];            // sqk partials [0..7], qb2 [8..15]
    __shared__ float  red16[16][Dd];        // QK/G partials; pass-2; tail

    int bx = blockIdx.x;                    // b*64 + l
    int l = bx & 63, b = bx >> 6;
    int tid = threadIdx.x;
    int wv = tid >> 6, lane = tid & 63;     // 16 waves

    // ---- stage (global -> LDS) ----
    if (tid < Dd) {
        zs[tid] = z[(size_t)l * Dd + tid];
    } else {
        int t = tid - Dd;
        float vb = 0.f;
#pragma unroll
        for (int j = 0; j < 8; ++j) vb += vb8[j * Dd + t];
        wpack[t] = make_float4(W1[2 * t], W1[2 * t + 1], b1[t], vb);
    }
    if (tid < Pp) {
        int row = bx * Pp + tid;
        float x = coords[(size_t)row * 2], y = coords[(size_t)row * 2 + 1];
        scx[tid] = (x - cstats[b * 4 + 0]) / cstats[b * 4 + 2];
        scy[tid] = (y - cstats[b * 4 + 1]) / cstats[b * 4 + 3];
    }
    __syncthreads();

    // ---- issue ALL feats loads (8 rows/wave) ----
    const float* fbase = feats + (size_t)bx * Pp * Dd;
    int rb = wv * 8;
    float4 f0[8], f1[8];
#pragma unroll
    for (int i = 0; i < 8; ++i) {
        const float4* fr = (const float4*)(fbase + (size_t)(rb + i) * Dd);
        f0[i] = fr[lane];
        f1[i] = fr[lane + 64];
    }
    __builtin_amdgcn_sched_barrier(0);      // pin: loads stay above QK compute

    // ---- QK/G rows from M1/M2 (L2-resident; overlaps feats HBM latency) ----
    {
        int h = tid >> 7, c4 = (tid & 127) * 4;     // 8 d-groups x 128 col-quads
        float4 aq = make_float4(0.f, 0.f, 0.f, 0.f);
        float4 ag = make_float4(0.f, 0.f, 0.f, 0.f);
        for (int d = h * 64; d < h * 64 + 64; ++d) {
            float zd = zs[d];                       // wave-uniform broadcast
            float4 m1 = *(const float4*)&M1[(size_t)d * Dd + c4];
            float4 m2 = *(const float4*)&M2[(size_t)d * Dd + c4];
            aq.x = fmaf(zd, m1.x, aq.x); aq.y = fmaf(zd, m1.y, aq.y);
            aq.z = fmaf(zd, m1.z, aq.z); aq.w = fmaf(zd, m1.w, aq.w);
            ag.x = fmaf(zd, m2.x, ag.x); ag.y = fmaf(zd, m2.y, ag.y);
            ag.z = fmaf(zd, m2.z, ag.z); ag.w = fmaf(zd, m2.w, ag.w);
        }
        *(float4*)&red16[h][c4]     = aq;
        *(float4*)&red16[8 + h][c4] = ag;
    }

    // ---- window coord means, per-wave in registers (scx/scy already sync'd)
    float cmx[4], cmy[4];
#pragma unroll
    for (int n = 0; n < 4; ++n) {
        int nv = (n == 3) ? 32 : 64;
        float cx = (lane < nv) ? scx[n * Ss + lane] : 0.f;
        float cy = (lane < nv) ? scy[n * Ss + lane] : 0.f;
        for (int o = 32; o > 0; o >>= 1) { cx += __shfl_xor(cx, o); cy += __shfl_xor(cy, o); }
        cmx[n] = cx / (float)nv; cmy[n] = cy / (float)nv;
    }
    __syncthreads();                        // QK/G partials ready

    // ---- reduce QK/G partials; sqk + qb2 wave partials ----
    if (tid < Dd) {
        float vq = 0.f, vg = 0.f;
#pragma unroll
        for (int h = 0; h < 8; ++h) { vq += red16[h][tid]; vg += red16[8 + h][tid]; }
        qk_s[tid] = vq; gw[tid] = vg;
        float pq = vq;
        float pb = zs[tid] * wpack[tid].w;
        for (int o = 32; o > 0; o >>= 1) { pq += __shfl_xor(pq, o); pb += __shfl_xor(pb, o); }
        if (lane == 0) { redsc[wv] = pq; redsc[8 + wv] = pb; }   // wv in 0..7
    }
    __syncthreads();                        // qk_s, gw, redsc ready
    float sqk_l = redsc[0] + redsc[1] + redsc[2] + redsc[3]
                + redsc[4] + redsc[5] + redsc[6] + redsc[7];
    float qb2_l = redsc[8] + redsc[9] + redsc[10] + redsc[11]
                + redsc[12] + redsc[13] + redsc[14] + redsc[15];

    // ---- pos-bias (LDS phase; remaining feats loads stream underneath) ----
    {
        int s = tid >> 2, q = tid & 3;
        int n = s >> 6, w = s & 63;
        int nv = (n == 3) ? 32 : 64;
        float hs = 0.f;
        if (w < nv) {
            int p = n * Ss + w;
            float px = scx[p] - cmx[n], py = scy[p] - cmy[n];
            int d0 = q * 128;
#pragma unroll 4
            for (int d = d0; d < d0 + 128; ++d) {
                float4 c = wpack[d];
                hs = fmaf(gw[d], fmaxf(fmaf(c.x, px, fmaf(c.y, py, c.z)), 0.f), hs);
            }
        }
        hs += __shfl_xor(hs, 1);
        hs += __shfl_xor(hs, 2);
        if (q == 0) shs[s] = hs;
    }

    // ---- row stats from registers (consumes the feats loads) ----
    {
        float4 q0 = ((const float4*)qk_s)[lane];
        float4 q1 = ((const float4*)qk_s)[lane + 64];
#pragma unroll
        for (int b2i = 0; b2i < 8; b2i += 4) {
            float sP[4], ssP[4], aP[4];
#pragma unroll
            for (int i = 0; i < 4; ++i) {
                float4 v0 = f0[b2i + i], v1 = f1[b2i + i];
                sP[i]  = v0.x + v0.y + v0.z + v0.w + v1.x + v1.y + v1.z + v1.w;
                ssP[i] = v0.x * v0.x + v0.y * v0.y + v0.z * v0.z + v0.w * v0.w
                       + v1.x * v1.x + v1.y * v1.y + v1.z * v1.z + v1.w * v1.w;
                aP[i]  = v0.x * q0.x + v0.y * q0.y + v0.z * q0.z + v0.w * q0.w
                       + v1.x * q1.x + v1.y * q1.y + v1.z * q1.z + v1.w * q1.w;
            }
#pragma unroll
            for (int o = 32; o > 0; o >>= 1) {
#pragma unroll
                for (int i = 0; i < 4; ++i) {
                    sP[i] += __shfl_xor(sP[i], o); ssP[i] += __shfl_xor(ssP[i], o);
                    aP[i] += __shfl_xor(aP[i], o);
                }
            }
            if (lane == 0) {
#pragma unroll
                for (int i = 0; i < 4; ++i) {
                    int r = rb + b2i + i;
                    float mu  = sP[i] * (1.f / (float)Dd);
                    float var = ssP[i] * (1.f / (float)Dd) - mu * mu;
                    smu[r] = mu; srs[r] = 1.f / sqrtf(var + 1e-5f); sa[r] = aP[i];
                }
            }
        }
    }
    __syncthreads();

    // ---- softmax per window (waves 0..3) ----
    const float invtemp = 0.04419417382415922f; // 1/sqrt(512)
    if (wv < 4) {
        int n = wv, w = lane;
        int nv = (n == 3) ? 32 : 64;
        int p = n * Ss + ((w < nv) ? w : 0);
        float lg = -1e30f;
        if (w < nv) {
            lg = (srs[p] * (sa[p] - smu[p] * sqk_l) + shs[n * Ww + w] + qb2_l) * invtemp;
            lg = fminf(fmaxf(lg, -10.f), 10.f);
        }
        float m = lg;
        for (int o = 32; o > 0; o >>= 1) m = fmaxf(m, __shfl_xor(m, o));
        float e = (w < nv) ? expf(lg - m) : 0.f;
        float ssum = e;
        for (int o = 32; o > 0; o >>= 1) ssum += __shfl_xor(ssum, o);
        float ar = (w < nv) ? (e / ssum) * srs[p] : 0.f;
        sar[n][w] = ar;
        float t2 = (w < nv) ? ar * smu[p] : 0.f;
        for (int o = 32; o > 0; o >>= 1) t2 += __shfl_xor(t2, o);
        if (lane == 0) s2red[n] = t2;
    }
    __syncthreads();

    // ---- combine per-row weights across (<=2) covering windows ----
    if (tid < Pp) {
        int p = tid;
        int na = (p >> 5) - 1, nb = (p >> 5);
        float wt = 0.f;
        if (na >= 0 && na <= 3) wt += sar[na][p - na * Ss];
        if (nb <= 3)            wt += sar[nb][p - nb * Ss];
        swt[p] = wt;
    }
    if (tid == 0) soff = 0.25f * (s2red[0] + s2red[1] + s2red[2] + s2red[3]);
    __syncthreads();

    // ---- pass 2: weighted feature sum FROM REGISTERS ----
    {
        float4 a0 = make_float4(0.f, 0.f, 0.f, 0.f);
        float4 a1 = make_float4(0.f, 0.f, 0.f, 0.f);
#pragma unroll
        for (int i = 0; i < 8; ++i) {
            float wt = swt[rb + i];         // wave-uniform LDS broadcast
            a0.x = fmaf(wt, f0[i].x, a0.x); a0.y = fmaf(wt, f0[i].y, a0.y);
            a0.z = fmaf(wt, f0[i].z, a0.z); a0.w = fmaf(wt, f0[i].w, a0.w);
            a1.x = fmaf(wt, f1[i].x, a1.x); a1.y = fmaf(wt, f1[i].y, a1.y);
            a1.z = fmaf(wt, f1[i].z, a1.z); a1.w = fmaf(wt, f1[i].w, a1.w);
        }
        *(float4*)&red16[wv][lane * 4]       = a0;
        *(float4*)&red16[wv][256 + lane * 4] = a1;
    }
    __syncthreads();
    if (tid < Dd) {
        float v = 0.f;
#pragma unroll
        for (int w = 0; w < 16; ++w) v += red16[w][tid];
        qk_s[tid] = 0.25f * v - soff;       // qk_s reused as fm
    }
    __syncthreads();

    // ---- tail: out = fm @ WvoT + bo (coalesced, L2-resident WvoT) ----
    {
        int h = tid >> 7, cq = (tid & 127) * 4;     // 8 e-groups of 64
        float4 acc = make_float4(0.f, 0.f, 0.f, 0.f);
#pragma unroll 4
        for (int e = h * 64; e < h * 64 + 64; ++e) {
            float fe = qk_s[e];
            float4 w = *(const float4*)&WvoT[(size_t)e * Dd + cq];
            acc.x = fmaf(fe, w.x, acc.x);
            acc.y = fmaf(fe, w.y, acc.y);
            acc.z = fmaf(fe, w.z, acc.z);
            acc.w = fmaf(fe, w.w, acc.w);
        }
        *(float4*)&red16[h][cq] = acc;
    }
    __syncthreads();
    if (tid < Dd) {
        out[(size_t)bx * Dd + tid] = bo[tid]
            + red16[0][tid] + red16[1][tid] + red16[2][tid] + red16[3][tid]
            + red16[4][tid] + red16[5][tid] + red16[6][tid] + red16[7][tid];
    }
}

// ---------------------------------------------------------------------------
extern "C" void kernel_launch(void* const* d_in, const int* in_sizes, int n_in,
                              void* d_out, int out_size, void* d_ws, size_t ws_size,
                              hipStream_t stream) {
    const float* feats  = (const float*)d_in[0];
    const float* coords = (const float*)d_in[1];
    // d_in[2] = mask, unused (all false, and unused by the reference body)
    const float* z  = (const float*)d_in[3];
    const float* Wq = (const float*)d_in[4];
    const float* Wk = (const float*)d_in[5];
    const float* Wv = (const float*)d_in[6];
    const float* W1 = (const float*)d_in[7];
    const float* b1 = (const float*)d_in[8];
    const float* W2 = (const float*)d_in[9];
    const float* b2 = (const float*)d_in[10];
    const float* Wo = (const float*)d_in[11];
    const float* bo = (const float*)d_in[12];
    float* out = (float*)d_out;

    // workspace layout (floats) — nothing needs pre-zeroing (~3.2 MB)
    float* ws = (float*)d_ws;
    float* cstats = ws;                         // 16
    float* M1     = ws + 16;                    // 512*512
    float* M2     = M1 + Dd * Dd;               // 512*512
    float* WvoT   = M2 + Dd * Dd;               // 512*512
    float* vb8    = WvoT + Dd * Dd;             // 8*512

    pre1<<<204, 256, 0, stream>>>(coords, b2, Wq, Wk, W2, Wv, Wo,
                                  cstats, M1, M2, WvoT, vb8);
    attn3<<<Bz * Ll, 1024, 0, stream>>>(feats, coords, cstats,
                                        M1, M2, vb8, z, W1, b1,
                                        WvoT, bo, out);
}

// Round 9
// 167.193 us; speedup vs baseline: 2.3166x; 1.2630x over previous
//
#include <hip/hip_runtime.h>

// Sizes fixed by the problem.
#define Bz 4
#define Nn 8192
#define Dd 512
#define Ll 64
#define Pp 128
#define Ww 64
#define Ss 32
#define NW 4   // number of window starts per segment

// wpack bank-conflict pad: 2-float4 gap every 128 rows. Lanes q=0..3 read
// d in {i,128+i,256+i,384+i}; unpadded these hit the same 4 LDS banks
// (stride 2048B). Padded: byte base 16*(130q+i) -> bank groups 0/8/16/24.
#define WPI(d) ((d) + 2 * ((d) >> 7))

// ---------------------------------------------------------------------------
// pre1: fully parallel preprocessing, 204 blocks x 256 threads (R6 verbatim).
//   [0,64):    M1 = Wq^T @ Wk   (64x64 tiles, 4x4 register blocking)
//   [64,128):  M2 = Wq^T @ W2
//   [128,192): WvoT[e,d] = sum_c Wv[c,e] Wo[d,c]
//   [192,200): vb8[j] = partial Wq^T @ b2 over e in [j*64,(j+1)*64)
//   [200,204): per-batch coord stats (mean + std ddof=1)
__global__ __launch_bounds__(256) void pre1(
    const float* __restrict__ coords, const float* __restrict__ b2,
    const float* __restrict__ Wq, const float* __restrict__ Wk,
    const float* __restrict__ W2,
    const float* __restrict__ Wv, const float* __restrict__ Wo,
    float* __restrict__ cstats,
    float* __restrict__ M1, float* __restrict__ M2,
    float* __restrict__ WvoT, float* __restrict__ vb8) {
    __shared__ float As[64][68];    // [k][m], 272B rows (16B-aligned)
    __shared__ float Bs[64][68];    // [k][n]
    __shared__ float b2s[64];
    __shared__ double dred[16];
    int bid = blockIdx.x, tid = threadIdx.x;
    int wv = tid >> 6, lane = tid & 63;

    if (bid < 192) {
        int role = bid >> 6;            // 0=M1, 1=M2, 2=WvoT
        int wb = bid & 63;
        int m0 = (wb >> 3) * 64;
        int n0 = (wb & 7) * 64;
        const float* Amat = (role == 2) ? Wv : Wq;
        const float* Bmat = (role == 0) ? Wk : (role == 1) ? W2 : Wo;
        float* Cmat = (role == 0) ? M1 : (role == 1) ? M2 : WvoT;
        int tx = tid & 15, ty = tid >> 4;       // 16x16 thread grid, 4x4 each
        float4 acc[4];
#pragma unroll
        for (int i = 0; i < 4; ++i) acc[i] = make_float4(0.f, 0.f, 0.f, 0.f);

        for (int k0 = 0; k0 < Dd; k0 += 64) {
            {
                int kk = tid >> 4, q4 = (tid & 15) * 4;
#pragma unroll
                for (int i = 0; i < 4; ++i) {
                    int k = kk + 16 * i;
                    *(float4*)&As[k][q4] =
                        *(const float4*)&Amat[(size_t)(k0 + k) * Dd + m0 + q4];
                }
                if (role != 2) {
#pragma unroll
                    for (int i = 0; i < 4; ++i) {
                        int k = kk + 16 * i;
                        *(float4*)&Bs[k][q4] =
                            *(const float4*)&Bmat[(size_t)(k0 + k) * Dd + n0 + q4];
                    }
                } else {
                    // B = Wo[d][c]: read rows coalesced, transpose-store Bs[c][d]
                    int d = tid >> 2;
#pragma unroll
                    for (int j = 0; j < 4; ++j) {
                        int c0 = (tid & 3) * 16 + 4 * j;
                        float4 v = *(const float4*)&Bmat[(size_t)(n0 + d) * Dd + k0 + c0];
                        Bs[c0 + 0][d] = v.x; Bs[c0 + 1][d] = v.y;
                        Bs[c0 + 2][d] = v.z; Bs[c0 + 3][d] = v.w;
                    }
                }
            }
            __syncthreads();
#pragma unroll 8
            for (int kk = 0; kk < 64; ++kk) {
                float4 a4 = *(const float4*)&As[kk][ty * 4];
                float4 b4 = *(const float4*)&Bs[kk][tx * 4];
                acc[0].x = fmaf(a4.x, b4.x, acc[0].x); acc[0].y = fmaf(a4.x, b4.y, acc[0].y);
                acc[0].z = fmaf(a4.x, b4.z, acc[0].z); acc[0].w = fmaf(a4.x, b4.w, acc[0].w);
                acc[1].x = fmaf(a4.y, b4.x, acc[1].x); acc[1].y = fmaf(a4.y, b4.y, acc[1].y);
                acc[1].z = fmaf(a4.y, b4.z, acc[1].z); acc[1].w = fmaf(a4.y, b4.w, acc[1].w);
                acc[2].x = fmaf(a4.z, b4.x, acc[2].x); acc[2].y = fmaf(a4.z, b4.y, acc[2].y);
                acc[2].z = fmaf(a4.z, b4.z, acc[2].z); acc[2].w = fmaf(a4.z, b4.w, acc[2].w);
                acc[3].x = fmaf(a4.w, b4.x, acc[3].x); acc[3].y = fmaf(a4.w, b4.y, acc[3].y);
                acc[3].z = fmaf(a4.w, b4.z, acc[3].z); acc[3].w = fmaf(a4.w, b4.w, acc[3].w);
            }
            __syncthreads();
        }
#pragma unroll
        for (int i = 0; i < 4; ++i)
            *(float4*)&Cmat[(size_t)(m0 + ty * 4 + i) * Dd + n0 + tx * 4] = acc[i];
    } else if (bid < 200) {
        // ---- vb8 partial: e-range [j*64, j*64+64) ----
        int j = bid - 192;
        if (tid < 64) b2s[tid] = b2[j * 64 + tid];
        __syncthreads();
        float a0 = 0.f, a1 = 0.f;
#pragma unroll 4
        for (int ee = 0; ee < 64; ++ee) {
            int e = j * 64 + ee;
            float be = b2s[ee];
            a0 = fmaf(be, Wq[(size_t)e * Dd + tid], a0);
            a1 = fmaf(be, Wq[(size_t)e * Dd + tid + 256], a1);
        }
        vb8[j * Dd + tid] = a0;
        vb8[j * Dd + tid + 256] = a1;
    } else {
        // ---- coord stats ----
        int b = bid - 200;
        double sx = 0, sy = 0, sxx = 0, syy = 0;
        const float4* cp = (const float4*)(coords + (size_t)b * Nn * 2);
        for (int i = tid; i < Nn / 2; i += 256) {      // 2 points per float4
            float4 v = cp[i];
            sx  += (double)v.x + (double)v.z;
            sy  += (double)v.y + (double)v.w;
            sxx += (double)v.x * v.x + (double)v.z * v.z;
            syy += (double)v.y * v.y + (double)v.w * v.w;
        }
        for (int o = 32; o > 0; o >>= 1) {
            sx  += __shfl_down(sx,  o); sy  += __shfl_down(sy,  o);
            sxx += __shfl_down(sxx, o); syy += __shfl_down(syy, o);
        }
        if (lane == 0) {
            dred[wv * 4 + 0] = sx;  dred[wv * 4 + 1] = sy;
            dred[wv * 4 + 2] = sxx; dred[wv * 4 + 3] = syy;
        }
        __syncthreads();
        if (tid == 0) {
            double tx = 0, ty = 0, txx = 0, tyy = 0;
            for (int i = 0; i < 4; ++i) {
                tx += dred[i * 4 + 0]; ty += dred[i * 4 + 1];
                txx += dred[i * 4 + 2]; tyy += dred[i * 4 + 3];
            }
            const double N = (double)Nn;
            double mux = tx / N, muy = ty / N;
            double vx = (txx - N * mux * mux) / (N - 1.0);
            double vy = (tyy - N * muy * muy) / (N - 1.0);
            cstats[b * 4 + 0] = (float)mux;
            cstats[b * 4 + 1] = (float)muy;
            cstats[b * 4 + 2] = (float)sqrt(vx) + 1e-8f;
            cstats[b * 4 + 3] = (float)sqrt(vy) + 1e-8f;
        }
    }
}

// ---------------------------------------------------------------------------
// qkg_k: QK[l,:] = z[l] @ M1, G[l,:] = z[l] @ M2 (128-col chunk per block),
// sqk4 partial row-sum, qb2[l] = z[l] . vb (ch==0 blocks). 256 blocks.
__global__ __launch_bounds__(256) void qkg_k(
    const float* __restrict__ z, const float* __restrict__ M1,
    const float* __restrict__ M2, const float* __restrict__ vb8,
    float* __restrict__ QK, float* __restrict__ G,
    float* __restrict__ sqk4, float* __restrict__ qb2) {
    __shared__ float zs[Dd];
    __shared__ float pq[8][128];
    __shared__ float pg[8][128];
    __shared__ float red[8];
    int bid = blockIdx.x, tid = threadIdx.x;
    int l = bid & 63, ch = bid >> 6;
    int wv = tid >> 6, lane = tid & 63;

    zs[tid]       = z[(size_t)l * Dd + tid];
    zs[tid + 256] = z[(size_t)l * Dd + tid + 256];
    __syncthreads();

    if (ch == 0) {
        float vba = 0.f, vbb = 0.f;
#pragma unroll
        for (int j = 0; j < 8; ++j) {
            vba += vb8[j * Dd + tid];
            vbb += vb8[j * Dd + tid + 256];
        }
        float p = zs[tid] * vba + zs[tid + 256] * vbb;
        for (int o = 32; o > 0; o >>= 1) p += __shfl_xor(p, o);
        if (lane == 0) red[4 + wv] = p;
    }

    // chunk: col-quad qd, d-group h (8 groups of 64)
    {
        int qd = tid & 31, h = tid >> 5;
        int cb = ch * 128 + qd * 4;
        float4 aq = make_float4(0.f, 0.f, 0.f, 0.f);
        float4 ag = make_float4(0.f, 0.f, 0.f, 0.f);
        for (int d = h * 64; d < h * 64 + 64; ++d) {
            float zd = zs[d];
            float4 m1 = *(const float4*)&M1[(size_t)d * Dd + cb];
            float4 m2 = *(const float4*)&M2[(size_t)d * Dd + cb];
            aq.x = fmaf(zd, m1.x, aq.x); aq.y = fmaf(zd, m1.y, aq.y);
            aq.z = fmaf(zd, m1.z, aq.z); aq.w = fmaf(zd, m1.w, aq.w);
            ag.x = fmaf(zd, m2.x, ag.x); ag.y = fmaf(zd, m2.y, ag.y);
            ag.z = fmaf(zd, m2.z, ag.z); ag.w = fmaf(zd, m2.w, ag.w);
        }
        *(float4*)&pq[h][qd * 4] = aq;
        *(float4*)&pg[h][qd * 4] = ag;
    }
    __syncthreads();
    if (tid < 128) {
        float vq = 0.f, vg = 0.f;
#pragma unroll
        for (int hh = 0; hh < 8; ++hh) { vq += pq[hh][tid]; vg += pg[hh][tid]; }
        QK[(size_t)l * Dd + ch * 128 + tid] = vq;
        G [(size_t)l * Dd + ch * 128 + tid] = vg;
        float s = vq;
        for (int o = 32; o > 0; o >>= 1) s += __shfl_xor(s, o);
        if (lane == 0) red[wv] = s;     // wv in {0,1}
    }
    __syncthreads();
    if (tid == 0) sqk4[ch * 64 + l] = red[0] + red[1];
    if (ch == 0 && tid == 32) qb2[l] = red[4] + red[5] + red[6] + red[7];
}

// ---------------------------------------------------------------------------
// Fused attention + output projection: one block per (b,l), 1024 threads.
// R6 body; wpack uses the WPI padded index to kill the 4-way pos-bias
// bank conflict (was ~9us/block of conflict cycles).
__global__ __launch_bounds__(1024) void attn2(
    const float* __restrict__ feats, const float* __restrict__ coords,
    const float* __restrict__ cstats,
    const float* __restrict__ QKm, const float* __restrict__ Gm,
    const float* __restrict__ sqk4, const float* __restrict__ qb2,
    const float* __restrict__ W1, const float* __restrict__ b1,
    const float* __restrict__ WvoT, const float* __restrict__ bo,
    float* __restrict__ out) {
    __shared__ float  qk_s[Dd];             // QK row; later reused as fm
    __shared__ float4 wpack[Dd + 8];        // {w1a, w1b, b1, g}, WPI-padded
    __shared__ float  scx[Pp], scy[Pp];
    __shared__ float  smu[Pp], srs[Pp], sa[Pp];
    __shared__ float  shs[NW * Ww];
    __shared__ float  sar[NW][Ww];
    __shared__ float  swt[Pp];
    __shared__ float  s2red[NW];
    __shared__ float  soff;
    __shared__ float  red16[16][Dd];        // pass-2 partials; rows 0..7 reused by tail

    int bx = blockIdx.x;                    // b*64 + l
    int l = bx & 63, b = bx >> 6;
    int tid = threadIdx.x;
    int wv = tid >> 6, lane = tid & 63;     // 16 waves

    // ---- stage (global -> LDS) ----
    if (tid < Dd) {
        qk_s[tid] = QKm[l * Dd + tid];
    } else {
        int t = tid - Dd;
        wpack[WPI(t)] = make_float4(W1[2 * t], W1[2 * t + 1], b1[t], Gm[l * Dd + t]);
    }
    if (tid < Pp) {
        int row = bx * Pp + tid;
        float x = coords[(size_t)row * 2], y = coords[(size_t)row * 2 + 1];
        scx[tid] = (x - cstats[b * 4 + 0]) / cstats[b * 4 + 2];
        scy[tid] = (y - cstats[b * 4 + 1]) / cstats[b * 4 + 3];
    }
    float sqk_l = sqk4[l] + sqk4[64 + l] + sqk4[128 + l] + sqk4[192 + l];
    float qb2_l = qb2[l];
    __syncthreads();

    // ---- issue ALL feats loads (8 rows/wave; lane owns cols lane*4 & 256+lane*4)
    const float* fbase = feats + (size_t)bx * Pp * Dd;
    int rb = wv * 8;
    float4 f0[8], f1[8];
#pragma unroll
    for (int i = 0; i < 8; ++i) {
        const float4* fr = (const float4*)(fbase + (size_t)(rb + i) * Dd);
        f0[i] = fr[lane];
        f1[i] = fr[lane + 64];
    }
    __builtin_amdgcn_sched_barrier(0);      // pin: loads stay above pos-bias

    // ---- window coord means, per-wave in registers (no barrier) ----
    float cmx[4], cmy[4];
#pragma unroll
    for (int n = 0; n < 4; ++n) {
        int nv = (n == 3) ? 32 : 64;
        float cx = (lane < nv) ? scx[n * Ss + lane] : 0.f;
        float cy = (lane < nv) ? scy[n * Ss + lane] : 0.f;
        for (int o = 32; o > 0; o >>= 1) { cx += __shfl_xor(cx, o); cy += __shfl_xor(cy, o); }
        cmx[n] = cx / (float)nv; cmy[n] = cy / (float)nv;
    }

    // ---- pos-bias (LDS phase; HBM loads stream underneath) ----
    {
        int s = tid >> 2, q = tid & 3;
        int n = s >> 6, w = s & 63;
        int nv = (n == 3) ? 32 : 64;
        float hs = 0.f;
        if (w < nv) {
            int p = n * Ss + w;
            float px = scx[p] - cmx[n], py = scy[p] - cmy[n];
            int d0 = q * 128;
#pragma unroll 4
            for (int i = 0; i < 128; ++i) {
                float4 c = wpack[WPI(d0) + i];   // = wpack[q*130 + i], affine
                hs = fmaf(c.w, fmaxf(fmaf(c.x, px, fmaf(c.y, py, c.z)), 0.f), hs);
            }
        }
        hs += __shfl_xor(hs, 1);
        hs += __shfl_xor(hs, 2);
        if (q == 0) shs[s] = hs;
    }

    // ---- row stats from registers (consumes the loads) ----
    {
        float4 q0 = ((const float4*)qk_s)[lane];
        float4 q1 = ((const float4*)qk_s)[lane + 64];
#pragma unroll
        for (int b2i = 0; b2i < 8; b2i += 4) {
            float sP[4], ssP[4], aP[4];
#pragma unroll
            for (int i = 0; i < 4; ++i) {
                float4 v0 = f0[b2i + i], v1 = f1[b2i + i];
                sP[i]  = v0.x + v0.y + v0.z + v0.w + v1.x + v1.y + v1.z + v1.w;
                ssP[i] = v0.x * v0.x + v0.y * v0.y + v0.z * v0.z + v0.w * v0.w
                       + v1.x * v1.x + v1.y * v1.y + v1.z * v1.z + v1.w * v1.w;
                aP[i]  = v0.x * q0.x + v0.y * q0.y + v0.z * q0.z + v0.w * q0.w
                       + v1.x * q1.x + v1.y * q1.y + v1.z * q1.z + v1.w * q1.w;
            }
#pragma unroll
            for (int o = 32; o > 0; o >>= 1) {
#pragma unroll
                for (int i = 0; i < 4; ++i) {
                    sP[i] += __shfl_xor(sP[i], o); ssP[i] += __shfl_xor(ssP[i], o);
                    aP[i] += __shfl_xor(aP[i], o);
                }
            }
            if (lane == 0) {
#pragma unroll
                for (int i = 0; i < 4; ++i) {
                    int r = rb + b2i + i;
                    float mu  = sP[i] * (1.f / (float)Dd);
                    float var = ssP[i] * (1.f / (float)Dd) - mu * mu;
                    smu[r] = mu; srs[r] = 1.f / sqrtf(var + 1e-5f); sa[r] = aP[i];
                }
            }
        }
    }
    __syncthreads();

    // ---- softmax per window (waves 0..3) ----
    const float invtemp = 0.04419417382415922f; // 1/sqrt(512)
    if (wv < 4) {
        int n = wv, w = lane;
        int nv = (n == 3) ? 32 : 64;
        int p = n * Ss + ((w < nv) ? w : 0);
        float lg = -1e30f;
        if (w < nv) {
            lg = (srs[p] * (sa[p] - smu[p] * sqk_l) + shs[n * Ww + w] + qb2_l) * invtemp;
            lg = fminf(fmaxf(lg, -10.f), 10.f);
        }
        float m = lg;
        for (int o = 32; o > 0; o >>= 1) m = fmaxf(m, __shfl_xor(m, o));
        float e = (w < nv) ? expf(lg - m) : 0.f;
        float ssum = e;
        for (int o = 32; o > 0; o >>= 1) ssum += __shfl_xor(ssum, o);
        float ar = (w < nv) ? (e / ssum) * srs[p] : 0.f;
        sar[n][w] = ar;
        float t2 = (w < nv) ? ar * smu[p] : 0.f;
        for (int o = 32; o > 0; o >>= 1) t2 += __shfl_xor(t2, o);
        if (lane == 0) s2red[n] = t2;
    }
    __syncthreads();

    // ---- combine per-row weights across (<=2) covering windows ----
    if (tid < Pp) {
        int p = tid;
        int na = (p >> 5) - 1, nb = (p >> 5);
        float wt = 0.f;
        if (na >= 0 && na <= 3) wt += sar[na][p - na * Ss];
        if (nb <= 3)            wt += sar[nb][p - nb * Ss];
        swt[p] = wt;
    }
    if (tid == 0) soff = 0.25f * (s2red[0] + s2red[1] + s2red[2] + s2red[3]);
    __syncthreads();

    // ---- pass 2: weighted feature sum FROM REGISTERS ----
    {
        float4 a0 = make_float4(0.f, 0.f, 0.f, 0.f);
        float4 a1 = make_float4(0.f, 0.f, 0.f, 0.f);
#pragma unroll
        for (int i = 0; i < 8; ++i) {
            float wt = swt[rb + i];         // wave-uniform LDS broadcast
            a0.x = fmaf(wt, f0[i].x, a0.x); a0.y = fmaf(wt, f0[i].y, a0.y);
            a0.z = fmaf(wt, f0[i].z, a0.z); a0.w = fmaf(wt, f0[i].w, a0.w);
            a1.x = fmaf(wt, f1[i].x, a1.x); a1.y = fmaf(wt, f1[i].y, a1.y);
            a1.z = fmaf(wt, f1[i].z, a1.z); a1.w = fmaf(wt, f1[i].w, a1.w);
        }
        *(float4*)&red16[wv][lane * 4]       = a0;
        *(float4*)&red16[wv][256 + lane * 4] = a1;
    }
    __syncthreads();
    if (tid < Dd) {
        float v = 0.f;
#pragma unroll
        for (int w = 0; w < 16; ++w) v += red16[w][tid];
        qk_s[tid] = 0.25f * v - soff;       // qk_s reused as fm
    }
    __syncthreads();

    // ---- tail: out = fm @ WvoT + bo (coalesced, L2-resident WvoT) ----
    {
        int h = tid >> 7, cq = (tid & 127) * 4; // 8 e-groups of 64
        float4 acc = make_float4(0.f, 0.f, 0.f, 0.f);
#pragma unroll 4
        for (int e = h * 64; e < h * 64 + 64; ++e) {
            float fe = qk_s[e];
            float4 w = *(const float4*)&WvoT[(size_t)e * Dd + cq];
            acc.x = fmaf(fe, w.x, acc.x);
            acc.y = fmaf(fe, w.y, acc.y);
            acc.z = fmaf(fe, w.z, acc.z);
            acc.w = fmaf(fe, w.w, acc.w);
        }
        *(float4*)&red16[h][cq] = acc;
    }
    __syncthreads();
    if (tid < Dd) {
        out[(size_t)bx * Dd + tid] = bo[tid]
            + red16[0][tid] + red16[1][tid] + red16[2][tid] + red16[3][tid]
            + red16[4][tid] + red16[5][tid] + red16[6][tid] + red16[7][tid];
    }
}

// ---------------------------------------------------------------------------
extern "C" void kernel_launch(void* const* d_in, const int* in_sizes, int n_in,
                              void* d_out, int out_size, void* d_ws, size_t ws_size,
                              hipStream_t stream) {
    const float* feats  = (const float*)d_in[0];
    const float* coords = (const float*)d_in[1];
    // d_in[2] = mask, unused (all false, and unused by the reference body)
    const float* z  = (const float*)d_in[3];
    const float* Wq = (const float*)d_in[4];
    const float* Wk = (const float*)d_in[5];
    const float* Wv = (const float*)d_in[6];
    const float* W1 = (const float*)d_in[7];
    const float* b1 = (const float*)d_in[8];
    const float* W2 = (const float*)d_in[9];
    const float* b2 = (const float*)d_in[10];
    const float* Wo = (const float*)d_in[11];
    const float* bo = (const float*)d_in[12];
    float* out = (float*)d_out;

    // workspace layout (floats) — nothing needs pre-zeroing (~3.3 MB)
    float* ws = (float*)d_ws;
    float* cstats = ws;                         // 16
    float* M1     = ws + 16;                    // 512*512
    float* M2     = M1 + Dd * Dd;               // 512*512
    float* WvoT   = M2 + Dd * Dd;               // 512*512
    float* vb8    = WvoT + Dd * Dd;             // 8*512
    float* QK     = vb8 + 8 * Dd;               // 64*512
    float* G      = QK + Ll * Dd;               // 64*512
    float* sqk4   = G + Ll * Dd;                // 256
    float* qb2    = sqk4 + 256;                 // 64

    pre1<<<204, 256, 0, stream>>>(coords, b2, Wq, Wk, W2, Wv, Wo,
                                  cstats, M1, M2, WvoT, vb8);
    qkg_k<<<256, 256, 0, stream>>>(z, M1, M2, vb8, QK, G, sqk4, qb2);
    attn2<<<Bz * Ll, 1024, 0, stream>>>(feats, coords, cstats,
                                        QK, G, sqk4, qb2, W1, b1,
                                        WvoT, bo, out);
}